// Round 12
// baseline (67.039 us; speedup 1.0000x reference)
//
#include <hip/hip_runtime.h>
#include <math.h>

// Setup: one thread computes tf_surface, tf_next (into d_out tail),
// and Minv/b/derived scalars (into d_ws). Runs once per launch; negligible.
__global__ void setup_k(const float* __restrict__ tf_in,
                        const float* __restrict__ diameter,
                        const float* __restrict__ C,
                        const float* __restrict__ anchors,
                        const float* __restrict__ scale,
                        float* __restrict__ tf_out,  // 32 floats: tf_surface, tf_next
                        float* __restrict__ ws) {
    float Cv = C[0], dia = diameter[0], sc = scale[0];
    float a0 = anchors[0] * dia * 0.5f;
    float a1 = anchors[1] * dia * 0.5f;
    float r20 = a0 * a0, r21 = a1 * a1;
    float sq0 = sqrtf(fmaxf(1.0f - Cv * Cv * r20, 1e-12f));
    float sq1 = sqrtf(fmaxf(1.0f - Cv * Cv * r21, 1e-12f));
    float ext0 = Cv * r20 / (1.0f + sq0);
    float ext1 = Cv * r21 / (1.0f + sq1);
    float dx0 = -sc * ext0;
    float dx1 = sc * (ext1 - ext0);

    float M[9], b[3];
    for (int r = 0; r < 4; ++r) {
        float t0 = tf_in[r*4+0], t1 = tf_in[r*4+1], t2 = tf_in[r*4+2], t3 = tf_in[r*4+3];
        tf_out[r*4+0] = t0 * sc;
        tf_out[r*4+1] = t1 * sc;
        tf_out[r*4+2] = t2 * sc;
        tf_out[r*4+3] = t0 * dx0 + t3;
        tf_out[16 + r*4+0] = t0;
        tf_out[16 + r*4+1] = t1;
        tf_out[16 + r*4+2] = t2;
        tf_out[16 + r*4+3] = t0 * dx1 + t3;
        if (r < 3) {
            M[r*3+0] = t0 * sc; M[r*3+1] = t1 * sc; M[r*3+2] = t2 * sc;
            b[r] = t0 * dx0 + t3;
        }
    }
    float c00 =  (M[4]*M[8] - M[5]*M[7]);
    float c01 = -(M[3]*M[8] - M[5]*M[6]);
    float c02 =  (M[3]*M[7] - M[4]*M[6]);
    float det = M[0]*c00 + M[1]*c01 + M[2]*c02;
    float id = 1.0f / det;
    float inv[9];
    inv[0] =  c00 * id;
    inv[1] = -(M[1]*M[8] - M[2]*M[7]) * id;
    inv[2] =  (M[1]*M[5] - M[2]*M[4]) * id;
    inv[3] =  c01 * id;
    inv[4] =  (M[0]*M[8] - M[2]*M[6]) * id;
    inv[5] = -(M[0]*M[5] - M[2]*M[3]) * id;
    inv[6] =  c02 * id;
    inv[7] = -(M[0]*M[7] - M[1]*M[6]) * id;
    inv[8] =  (M[0]*M[4] - M[1]*M[3]) * id;
    #pragma unroll
    for (int i = 0; i < 9; ++i) ws[i] = inv[i];
    ws[9]  = b[0]; ws[10] = b[1]; ws[11] = b[2];
    ws[12] = Cv;
    ws[13] = (dia * 0.5f) * (dia * 0.5f);  // rmax^2
    ws[14] = Cv * Cv;
    ws[15] = 1.0f / Cv;                    // invC
}

// Fast approx: v_rcp_f32 / v_rsq_f32, ~2^-22 rel err, single instruction.
__device__ __forceinline__ float frcp(float x) { return __builtin_amdgcn_rcpf(x); }
__device__ __forceinline__ float frsq(float x) { return __builtin_amdgcn_rsqf(x); }

typedef float fx4 __attribute__((ext_vector_type(4)));

// Explicit 4-wide SoA vector: keeps independent dependency chains live.
struct v4 { float a, b, c, d; };
__device__ __forceinline__ v4 vsub(v4 x, v4 y) { return {x.a-y.a, x.b-y.b, x.c-y.c, x.d-y.d}; }
__device__ __forceinline__ v4 vmul(v4 x, v4 y) { return {x.a*y.a, x.b*y.b, x.c*y.c, x.d*y.d}; }
__device__ __forceinline__ v4 vmuls(v4 x, float s) { return {x.a*s, x.b*s, x.c*s, x.d*s}; }
__device__ __forceinline__ v4 vfma(v4 x, v4 y, v4 z) {
    return {fmaf(x.a,y.a,z.a), fmaf(x.b,y.b,z.b), fmaf(x.c,y.c,z.c), fmaf(x.d,y.d,z.d)};
}
__device__ __forceinline__ v4 vfmas(v4 x, float s, v4 z) {  // x*s + z
    return {fmaf(x.a,s,z.a), fmaf(x.b,s,z.b), fmaf(x.c,s,z.c), fmaf(x.d,s,z.d)};
}
__device__ __forceinline__ v4 vmaxs(v4 x, float s) {
    return {fmaxf(x.a,s), fmaxf(x.b,s), fmaxf(x.c,s), fmaxf(x.d,s)};
}
__device__ __forceinline__ v4 vrsq(v4 x) { return {frsq(x.a), frsq(x.b), frsq(x.c), frsq(x.d)}; }
__device__ __forceinline__ v4 vrcp(v4 x) { return {frcp(x.a), frcp(x.b), frcp(x.c), frcp(x.d)}; }
__device__ __forceinline__ v4 vneg(v4 x) { return {-x.a, -x.b, -x.c, -x.d}; }
__device__ __forceinline__ float clampden(float x) { return (fabsf(x) > 1e-12f) ? x : 1e-12f; }
__device__ __forceinline__ v4 vclampden(v4 x) {
    return {clampden(x.a), clampden(x.b), clampden(x.c), clampden(x.d)};
}

struct res4 { v4 t, n0, n1, n2; fx4 vd; };

// 4 independent Newton chains (verified math from rounds 3/10).
__device__ __forceinline__ res4 newton4(
    v4 px, v4 py, v4 pz, v4 vx, v4 vy, v4 vz,
    float m00, float m01, float m02, float m10, float m11, float m12,
    float m20, float m21, float m22, float b0, float b1, float b2,
    float Cv, float rmax2, float cc, float invC) {
    v4 dpx = {px.a-b0, px.b-b0, px.c-b0, px.d-b0};
    v4 dpy = {py.a-b1, py.b-b1, py.c-b1, py.d-b1};
    v4 dpz = {pz.a-b2, pz.b-b2, pz.c-b2, pz.d-b2};
    v4 Pl0 = vfmas(dpx, m00, vfmas(dpy, m01, vmuls(dpz, m02)));
    v4 Pl1 = vfmas(dpx, m10, vfmas(dpy, m11, vmuls(dpz, m12)));
    v4 Pl2 = vfmas(dpx, m20, vfmas(dpy, m21, vmuls(dpz, m22)));
    v4 Vl0 = vfmas(vx, m00, vfmas(vy, m01, vmuls(vz, m02)));
    v4 Vl1 = vfmas(vx, m10, vfmas(vy, m11, vmuls(vz, m12)));
    v4 Vl2 = vfmas(vx, m20, vfmas(vy, m21, vmuls(vz, m22)));

    const v4 one = {1.0f, 1.0f, 1.0f, 1.0f};
    v4 t = {0.0f, 0.0f, 0.0f, 0.0f};
    #pragma unroll
    for (int it = 0; it < 6; ++it) {
        v4 q1 = vfma(t, Vl1, Pl1);
        v4 q2 = vfma(t, Vl2, Pl2);
        v4 r2 = vfma(q1, q1, vmul(q2, q2));
        v4 w  = vmaxs(vfmas(r2, -cc, one), 1e-12f);
        v4 rs = vrsq(w);
        v4 sq = vmul(w, rs);
        v4 d  = vmuls(rs, Cv);
        v4 sv = vfmas(sq, -invC, {invC, invC, invC, invC});   // (1-sq)/C
        v4 q0 = vfma(t, Vl0, Pl0);
        v4 F  = vsub(sv, q0);
        v4 dot = vfma(q2, Vl2, vmul(q1, Vl1));
        v4 denom = vclampden(vfma(d, dot, vneg(Vl0)));
        t = vfma(vneg(F), vrcp(denom), t);
    }
    v4 q0 = vfma(t, Vl0, Pl0);
    v4 q1 = vfma(t, Vl1, Pl1);
    v4 q2 = vfma(t, Vl2, Pl2);
    v4 r2 = vfma(q1, q1, vmul(q2, q2));
    v4 wp = vfmas(r2, -cc, one);
    v4 w  = vmaxs(wp, 1e-12f);
    v4 rs = vrsq(w);
    v4 sq = vmul(w, rs);
    v4 d  = vmuls(rs, Cv);
    v4 sv = vfmas(sq, -invC, {invC, invC, invC, invC});
    v4 F  = vsub(sv, q0);

    v4 g1 = vmul(d, q1), g2 = vmul(d, q2);
    v4 nm00 = {-m00,-m00,-m00,-m00}, nm01 = {-m01,-m01,-m01,-m01}, nm02 = {-m02,-m02,-m02,-m02};
    v4 n0 = vfmas(g1, m10, vfmas(g2, m20, nm00));
    v4 n1 = vfmas(g1, m11, vfmas(g2, m21, nm01));
    v4 n2 = vfmas(g1, m12, vfmas(g2, m22, nm02));
    v4 ninv = vrsq(vfma(n0, n0, vfma(n1, n1, vmul(n2, n2))));
    res4 r;
    r.t = t;
    r.n0 = vmul(n0, ninv); r.n1 = vmul(n1, ninv); r.n2 = vmul(n2, ninv);
    r.vd = (fx4){
        (r2.a <= rmax2 && fabsf(F.a) < 0.001f && wp.a > 0.0f) ? 1.0f : 0.0f,
        (r2.b <= rmax2 && fabsf(F.b) < 0.001f && wp.b > 0.0f) ? 1.0f : 0.0f,
        (r2.c <= rmax2 && fabsf(F.c) < 0.001f && wp.c > 0.0f) ? 1.0f : 0.0f,
        (r2.d <= rmax2 && fabsf(F.d) < 0.001f && wp.d > 0.0f) ? 1.0f : 0.0f};
    return r;
}

// Main kernel: 8 elements/thread (2048-elem tile, 256 threads). 12 float4
// loads in flight (2x MLP vs round 10) + 8 independent Newton chains (2x
// ILP). ALL outputs redistributed through one phase-reused 24KB LDS buffer
// so every global store is a contiguous full-line nt float4 (round-10: nt
// needs full lines or WRITE_SIZE inflates via partial-line RMW; nt keeps the
// 168MB/replay write-once stream from churning caches: 77.6->66.8us).
__global__ __launch_bounds__(256) void trace_k(
    const float4* __restrict__ P4, const float4* __restrict__ V4,
    const float* __restrict__ ws,
    fx4* __restrict__ t_out4, fx4* __restrict__ n_out4,
    fx4* __restrict__ valid_out4, int ntiles) {
    __shared__ float sB[6144];   // 24KB, phase-reused: n tile, then t+valid
    const int tid = threadIdx.x;
    const int blk = blockIdx.x;
    if (blk >= ntiles) return;

    const size_t fbase = (size_t)blk * 1536;   // float4 base of tile (P/V and n)

    // ---- 12 loads issued back-to-back: thread owns 8 consecutive elements ----
    float4 pr0 = P4[fbase + (size_t)tid*6 + 0];
    float4 pr1 = P4[fbase + (size_t)tid*6 + 1];
    float4 pr2 = P4[fbase + (size_t)tid*6 + 2];
    float4 pr3 = P4[fbase + (size_t)tid*6 + 3];
    float4 pr4 = P4[fbase + (size_t)tid*6 + 4];
    float4 pr5 = P4[fbase + (size_t)tid*6 + 5];
    float4 vr0 = V4[fbase + (size_t)tid*6 + 0];
    float4 vr1 = V4[fbase + (size_t)tid*6 + 1];
    float4 vr2 = V4[fbase + (size_t)tid*6 + 2];
    float4 vr3 = V4[fbase + (size_t)tid*6 + 3];
    float4 vr4 = V4[fbase + (size_t)tid*6 + 4];
    float4 vr5 = V4[fbase + (size_t)tid*6 + 5];

    const float m00 = ws[0], m01 = ws[1], m02 = ws[2];
    const float m10 = ws[3], m11 = ws[4], m12 = ws[5];
    const float m20 = ws[6], m21 = ws[7], m22 = ws[8];
    const float b0 = ws[9], b1 = ws[10], b2 = ws[11];
    const float Cv = ws[12], rmax2 = ws[13], cc = ws[14], invC = ws[15];

    // ---- unpack AoS -> two 4-wide SoA groups ----
    v4 pxL = {pr0.x, pr0.w, pr1.z, pr2.y};
    v4 pyL = {pr0.y, pr1.x, pr1.w, pr2.z};
    v4 pzL = {pr0.z, pr1.y, pr2.x, pr2.w};
    v4 vxL = {vr0.x, vr0.w, vr1.z, vr2.y};
    v4 vyL = {vr0.y, vr1.x, vr1.w, vr2.z};
    v4 vzL = {vr0.z, vr1.y, vr2.x, vr2.w};
    v4 pxH = {pr3.x, pr3.w, pr4.z, pr5.y};
    v4 pyH = {pr3.y, pr4.x, pr4.w, pr5.z};
    v4 pzH = {pr3.z, pr4.y, pr5.x, pr5.w};
    v4 vxH = {vr3.x, vr3.w, vr4.z, vr5.y};
    v4 vyH = {vr3.y, vr4.x, vr4.w, vr5.z};
    v4 vzH = {vr3.z, vr4.y, vr5.x, vr5.w};

    res4 lo = newton4(pxL, pyL, pzL, vxL, vyL, vzL,
                      m00,m01,m02,m10,m11,m12,m20,m21,m22,b0,b1,b2,Cv,rmax2,cc,invC);
    res4 hi = newton4(pxH, pyH, pzH, vxH, vyH, vzH,
                      m00,m01,m02,m10,m11,m12,m20,m21,m22,b0,b1,b2,Cv,rmax2,cc,invC);

    // ---- phase A: n tile through LDS (thread writes 24 contiguous floats) ----
    fx4* sB4 = (fx4*)sB;
    sB4[tid*6 + 0] = (fx4){lo.n0.a, lo.n1.a, lo.n2.a, lo.n0.b};
    sB4[tid*6 + 1] = (fx4){lo.n1.b, lo.n2.b, lo.n0.c, lo.n1.c};
    sB4[tid*6 + 2] = (fx4){lo.n2.c, lo.n0.d, lo.n1.d, lo.n2.d};
    sB4[tid*6 + 3] = (fx4){hi.n0.a, hi.n1.a, hi.n2.a, hi.n0.b};
    sB4[tid*6 + 4] = (fx4){hi.n1.b, hi.n2.b, hi.n0.c, hi.n1.c};
    sB4[tid*6 + 5] = (fx4){hi.n2.c, hi.n0.d, hi.n1.d, hi.n2.d};
    __syncthreads();
    #pragma unroll
    for (int q = 0; q < 6; ++q) {
        __builtin_nontemporal_store(sB4[q*256 + tid], &n_out4[fbase + q*256 + tid]);
    }
    __syncthreads();   // all reads done before phase B overwrites

    // ---- phase B: t (8KB) + valid (8KB) through same buffer ----
    sB4[tid*2 + 0]       = (fx4){lo.t.a, lo.t.b, lo.t.c, lo.t.d};
    sB4[tid*2 + 1]       = (fx4){hi.t.a, hi.t.b, hi.t.c, hi.t.d};
    sB4[512 + tid*2 + 0] = lo.vd;
    sB4[512 + tid*2 + 1] = hi.vd;
    __syncthreads();
    const size_t tbase = (size_t)blk * 512;
    __builtin_nontemporal_store(sB4[tid],         &t_out4[tbase + tid]);
    __builtin_nontemporal_store(sB4[256 + tid],   &t_out4[tbase + 256 + tid]);
    __builtin_nontemporal_store(sB4[512 + tid],   &valid_out4[tbase + tid]);
    __builtin_nontemporal_store(sB4[768 + tid],   &valid_out4[tbase + 256 + tid]);
}

// Scalar tail for N % 2048 != 0 (not hit at N=2^23, but safe).
__global__ void trace_tail_k(const float* __restrict__ P, const float* __restrict__ V,
                             const float* __restrict__ ws,
                             float* __restrict__ t_out, float* __restrict__ n_out,
                             float* __restrict__ valid_out, int start, int N) {
    int i = start + blockIdx.x * blockDim.x + threadIdx.x;
    if (i >= N) return;
    const float m00 = ws[0], m01 = ws[1], m02 = ws[2];
    const float m10 = ws[3], m11 = ws[4], m12 = ws[5];
    const float m20 = ws[6], m21 = ws[7], m22 = ws[8];
    const float b0 = ws[9], b1 = ws[10], b2 = ws[11];
    const float Cv = ws[12], rmax2 = ws[13], cc = ws[14], invC = ws[15];
    float dpx = P[i*3+0] - b0, dpy = P[i*3+1] - b1, dpz = P[i*3+2] - b2;
    float Pl0 = m00*dpx + m01*dpy + m02*dpz;
    float Pl1 = m10*dpx + m11*dpy + m12*dpz;
    float Pl2 = m20*dpx + m21*dpy + m22*dpz;
    float Vl0 = m00*V[i*3+0] + m01*V[i*3+1] + m02*V[i*3+2];
    float Vl1 = m10*V[i*3+0] + m11*V[i*3+1] + m12*V[i*3+2];
    float Vl2 = m20*V[i*3+0] + m21*V[i*3+1] + m22*V[i*3+2];
    float t = 0.0f;
    for (int it = 0; it < 6; ++it) {
        float q1 = Pl1 + t*Vl1, q2 = Pl2 + t*Vl2;
        float r2 = q1*q1 + q2*q2;
        float w  = fmaxf(1.0f - cc*r2, 1e-12f);
        float rs = frsq(w);
        float sq = w * rs;
        float d  = Cv * rs;
        float sv = fmaf(sq, -invC, invC);
        float F  = sv - (Pl0 + t*Vl0);
        float denom = d*(q1*Vl1 + q2*Vl2) - Vl0;
        denom = (fabsf(denom) > 1e-12f) ? denom : 1e-12f;
        t = t - F * frcp(denom);
    }
    float q0 = Pl0 + t*Vl0, q1 = Pl1 + t*Vl1, q2 = Pl2 + t*Vl2;
    float r2 = q1*q1 + q2*q2;
    float wp = 1.0f - cc*r2;
    float w  = fmaxf(wp, 1e-12f);
    float rs = frsq(w);
    float sq = w * rs;
    float d  = Cv * rs;
    float sv = fmaf(sq, -invC, invC);
    float F  = sv - q0;
    bool valid = (r2 <= rmax2) && (fabsf(F) < 0.001f) && (wp > 0.0f);
    float g1 = d*q1, g2 = d*q2;
    float n0 = -m00 + g1*m10 + g2*m20;
    float n1 = -m01 + g1*m11 + g2*m21;
    float n2 = -m02 + g1*m12 + g2*m22;
    float ninv = frsq(n0*n0 + n1*n1 + n2*n2);
    t_out[i] = t;
    n_out[i*3+0] = n0*ninv; n_out[i*3+1] = n1*ninv; n_out[i*3+2] = n2*ninv;
    valid_out[i] = valid ? 1.0f : 0.0f;
}

extern "C" void kernel_launch(void* const* d_in, const int* in_sizes, int n_in,
                              void* d_out, int out_size, void* d_ws, size_t ws_size,
                              hipStream_t stream) {
    const float* P       = (const float*)d_in[0];
    const float* V       = (const float*)d_in[1];
    const float* tf_in   = (const float*)d_in[2];
    const float* dia     = (const float*)d_in[3];
    const float* C       = (const float*)d_in[4];
    const float* anchors = (const float*)d_in[5];
    const float* scale   = (const float*)d_in[6];
    const int N = in_sizes[0] / 3;

    float* out = (float*)d_out;
    float* ws  = (float*)d_ws;

    // Output layout: t[N] | n[3N] | valid[N] | tf_surface[16] | tf_next[16]
    float* t_out     = out;
    float* n_out     = out + (size_t)N;
    float* valid_out = out + (size_t)4*N;
    float* tf_out    = out + (size_t)5*N;

    setup_k<<<1, 1, 0, stream>>>(tf_in, dia, C, anchors, scale, tf_out, ws);

    const int ntiles = N / 2048;
    if (ntiles > 0) {
        trace_k<<<ntiles, 256, 0, stream>>>((const float4*)P, (const float4*)V, ws,
                                            (fx4*)t_out, (fx4*)n_out,
                                            (fx4*)valid_out, ntiles);
    }
    const int start = ntiles * 2048;
    const int rem = N - start;
    if (rem > 0) {
        trace_tail_k<<<(rem + 255) / 256, 256, 0, stream>>>(P, V, ws, t_out, n_out,
                                                            valid_out, start, N);
    }
}

// Round 13
// 66.199 us; speedup vs baseline: 1.0127x; 1.0127x over previous
//
#include <hip/hip_runtime.h>
#include <math.h>

// Setup: one thread computes tf_surface, tf_next (into d_out tail),
// and Minv/b/derived scalars (into d_ws). Runs once per launch; negligible.
__global__ void setup_k(const float* __restrict__ tf_in,
                        const float* __restrict__ diameter,
                        const float* __restrict__ C,
                        const float* __restrict__ anchors,
                        const float* __restrict__ scale,
                        float* __restrict__ tf_out,  // 32 floats: tf_surface, tf_next
                        float* __restrict__ ws) {
    float Cv = C[0], dia = diameter[0], sc = scale[0];
    float a0 = anchors[0] * dia * 0.5f;
    float a1 = anchors[1] * dia * 0.5f;
    float r20 = a0 * a0, r21 = a1 * a1;
    float sq0 = sqrtf(fmaxf(1.0f - Cv * Cv * r20, 1e-12f));
    float sq1 = sqrtf(fmaxf(1.0f - Cv * Cv * r21, 1e-12f));
    float ext0 = Cv * r20 / (1.0f + sq0);
    float ext1 = Cv * r21 / (1.0f + sq1);
    float dx0 = -sc * ext0;
    float dx1 = sc * (ext1 - ext0);

    float M[9], b[3];
    for (int r = 0; r < 4; ++r) {
        float t0 = tf_in[r*4+0], t1 = tf_in[r*4+1], t2 = tf_in[r*4+2], t3 = tf_in[r*4+3];
        tf_out[r*4+0] = t0 * sc;
        tf_out[r*4+1] = t1 * sc;
        tf_out[r*4+2] = t2 * sc;
        tf_out[r*4+3] = t0 * dx0 + t3;
        tf_out[16 + r*4+0] = t0;
        tf_out[16 + r*4+1] = t1;
        tf_out[16 + r*4+2] = t2;
        tf_out[16 + r*4+3] = t0 * dx1 + t3;
        if (r < 3) {
            M[r*3+0] = t0 * sc; M[r*3+1] = t1 * sc; M[r*3+2] = t2 * sc;
            b[r] = t0 * dx0 + t3;
        }
    }
    float c00 =  (M[4]*M[8] - M[5]*M[7]);
    float c01 = -(M[3]*M[8] - M[5]*M[6]);
    float c02 =  (M[3]*M[7] - M[4]*M[6]);
    float det = M[0]*c00 + M[1]*c01 + M[2]*c02;
    float id = 1.0f / det;
    float inv[9];
    inv[0] =  c00 * id;
    inv[1] = -(M[1]*M[8] - M[2]*M[7]) * id;
    inv[2] =  (M[1]*M[5] - M[2]*M[4]) * id;
    inv[3] =  c01 * id;
    inv[4] =  (M[0]*M[8] - M[2]*M[6]) * id;
    inv[5] = -(M[0]*M[5] - M[2]*M[3]) * id;
    inv[6] =  c02 * id;
    inv[7] = -(M[0]*M[7] - M[1]*M[6]) * id;
    inv[8] =  (M[0]*M[4] - M[1]*M[3]) * id;
    #pragma unroll
    for (int i = 0; i < 9; ++i) ws[i] = inv[i];
    ws[9]  = b[0]; ws[10] = b[1]; ws[11] = b[2];
    ws[12] = Cv;
    ws[13] = (dia * 0.5f) * (dia * 0.5f);  // rmax^2
    ws[14] = Cv * Cv;
    ws[15] = 1.0f / Cv;                    // invC
}

// Fast approx: v_rcp_f32 / v_rsq_f32, ~2^-22 rel err, single instruction.
__device__ __forceinline__ float frcp(float x) { return __builtin_amdgcn_rcpf(x); }
__device__ __forceinline__ float frsq(float x) { return __builtin_amdgcn_rsqf(x); }

typedef float fx4 __attribute__((ext_vector_type(4)));

// Explicit 4-wide SoA vector: keeps independent dependency chains live.
struct v4 { float a, b, c, d; };
__device__ __forceinline__ v4 vsub(v4 x, v4 y) { return {x.a-y.a, x.b-y.b, x.c-y.c, x.d-y.d}; }
__device__ __forceinline__ v4 vmul(v4 x, v4 y) { return {x.a*y.a, x.b*y.b, x.c*y.c, x.d*y.d}; }
__device__ __forceinline__ v4 vmuls(v4 x, float s) { return {x.a*s, x.b*s, x.c*s, x.d*s}; }
__device__ __forceinline__ v4 vfma(v4 x, v4 y, v4 z) {
    return {fmaf(x.a,y.a,z.a), fmaf(x.b,y.b,z.b), fmaf(x.c,y.c,z.c), fmaf(x.d,y.d,z.d)};
}
__device__ __forceinline__ v4 vfmas(v4 x, float s, v4 z) {  // x*s + z
    return {fmaf(x.a,s,z.a), fmaf(x.b,s,z.b), fmaf(x.c,s,z.c), fmaf(x.d,s,z.d)};
}
__device__ __forceinline__ v4 vmaxs(v4 x, float s) {
    return {fmaxf(x.a,s), fmaxf(x.b,s), fmaxf(x.c,s), fmaxf(x.d,s)};
}
__device__ __forceinline__ v4 vrsq(v4 x) { return {frsq(x.a), frsq(x.b), frsq(x.c), frsq(x.d)}; }
__device__ __forceinline__ v4 vrcp(v4 x) { return {frcp(x.a), frcp(x.b), frcp(x.c), frcp(x.d)}; }
__device__ __forceinline__ v4 vneg(v4 x) { return {-x.a, -x.b, -x.c, -x.d}; }
__device__ __forceinline__ float clampden(float x) { return (fabsf(x) > 1e-12f) ? x : 1e-12f; }
__device__ __forceinline__ v4 vclampden(v4 x) {
    return {clampden(x.a), clampden(x.b), clampden(x.c), clampden(x.d)};
}

// Main kernel: 1024-elem tile, 256 threads, 4 elem/thread (interleaved
// ownership el = k*256+tid). ONE 12KB LDS buffer phase-reused (P stage ->
// V stage -> n out) so 8 blocks/CU fit (vs 6 at 24KB, occupancy 57% -> up
// to 100%). All global loads issue up front (6 float4 in flight). Output
// discipline from round 10 (66.8us win): scalar t/valid nt stores are
// stride-1 (256B/wave full lines); n redistributed through LDS with
// conflict-free patterns, then contiguous full-line nt float4 stores.
__global__ __launch_bounds__(256) void trace_k(
    const float4* __restrict__ P4, const float4* __restrict__ V4,
    const float* __restrict__ ws,
    float* __restrict__ t_out, fx4* __restrict__ n_out4,
    float* __restrict__ valid_out, int ntiles) {
    __shared__ float sB[3072];   // 12KB, phase-reused
    fx4* sB4 = (fx4*)sB;
    const int tid = threadIdx.x;
    const int blk = blockIdx.x;
    if (blk >= ntiles) return;

    const size_t fbase = (size_t)blk * 768;   // float4 index of tile start

    // ---- issue ALL global loads up front (6 in flight per thread) ----
    float4 pr0 = P4[fbase + 0*256 + tid];
    float4 pr1 = P4[fbase + 1*256 + tid];
    float4 pr2 = P4[fbase + 2*256 + tid];
    float4 vr0 = V4[fbase + 0*256 + tid];
    float4 vr1 = V4[fbase + 1*256 + tid];
    float4 vr2 = V4[fbase + 2*256 + tid];

    const float m00 = ws[0], m01 = ws[1], m02 = ws[2];
    const float m10 = ws[3], m11 = ws[4], m12 = ws[5];
    const float m20 = ws[6], m21 = ws[7], m22 = ws[8];
    const float b0 = ws[9], b1 = ws[10], b2 = ws[11];
    const float Cv = ws[12], rmax2 = ws[13], cc = ws[14], invC = ws[15];

    // ---- phase 1: P through LDS (contiguous fx4 writes, conflict-free) ----
    sB4[0*256 + tid] = (fx4){pr0.x, pr0.y, pr0.z, pr0.w};
    sB4[1*256 + tid] = (fx4){pr1.x, pr1.y, pr1.z, pr1.w};
    sB4[2*256 + tid] = (fx4){pr2.x, pr2.y, pr2.z, pr2.w};
    __syncthreads();
    float Pl0a[4], Pl1a[4], Pl2a[4];
    #pragma unroll
    for (int k = 0; k < 4; ++k) {
        const int el = k*256 + tid;           // stride-12B scalar reads: 2/bank, free
        float dpx = sB[el*3+0] - b0;
        float dpy = sB[el*3+1] - b1;
        float dpz = sB[el*3+2] - b2;
        Pl0a[k] = fmaf(dpx, m00, fmaf(dpy, m01, dpz*m02));
        Pl1a[k] = fmaf(dpx, m10, fmaf(dpy, m11, dpz*m12));
        Pl2a[k] = fmaf(dpx, m20, fmaf(dpy, m21, dpz*m22));
    }
    __syncthreads();

    // ---- phase 2: V through the same LDS buffer ----
    sB4[0*256 + tid] = (fx4){vr0.x, vr0.y, vr0.z, vr0.w};
    sB4[1*256 + tid] = (fx4){vr1.x, vr1.y, vr1.z, vr1.w};
    sB4[2*256 + tid] = (fx4){vr2.x, vr2.y, vr2.z, vr2.w};
    __syncthreads();
    float Vl0a[4], Vl1a[4], Vl2a[4];
    #pragma unroll
    for (int k = 0; k < 4; ++k) {
        const int el = k*256 + tid;
        float wx = sB[el*3+0], wy = sB[el*3+1], wz = sB[el*3+2];
        Vl0a[k] = fmaf(wx, m00, fmaf(wy, m01, wz*m02));
        Vl1a[k] = fmaf(wx, m10, fmaf(wy, m11, wz*m12));
        Vl2a[k] = fmaf(wx, m20, fmaf(wy, m21, wz*m22));
    }
    __syncthreads();

    v4 Pl0 = {Pl0a[0], Pl0a[1], Pl0a[2], Pl0a[3]};
    v4 Pl1 = {Pl1a[0], Pl1a[1], Pl1a[2], Pl1a[3]};
    v4 Pl2 = {Pl2a[0], Pl2a[1], Pl2a[2], Pl2a[3]};
    v4 Vl0 = {Vl0a[0], Vl0a[1], Vl0a[2], Vl0a[3]};
    v4 Vl1 = {Vl1a[0], Vl1a[1], Vl1a[2], Vl1a[3]};
    v4 Vl2 = {Vl2a[0], Vl2a[1], Vl2a[2], Vl2a[3]};

    // ---- 4-wide Newton (verified math, rounds 3/10) ----
    const v4 one = {1.0f, 1.0f, 1.0f, 1.0f};
    v4 t = {0.0f, 0.0f, 0.0f, 0.0f};
    #pragma unroll
    for (int it = 0; it < 6; ++it) {
        v4 q1 = vfma(t, Vl1, Pl1);
        v4 q2 = vfma(t, Vl2, Pl2);
        v4 r2 = vfma(q1, q1, vmul(q2, q2));
        v4 w  = vmaxs(vfmas(r2, -cc, one), 1e-12f);
        v4 rs = vrsq(w);
        v4 sq = vmul(w, rs);
        v4 d  = vmuls(rs, Cv);
        v4 sv = vfmas(sq, -invC, {invC, invC, invC, invC});   // (1-sq)/C
        v4 q0 = vfma(t, Vl0, Pl0);
        v4 F  = vsub(sv, q0);
        v4 dot = vfma(q2, Vl2, vmul(q1, Vl1));
        v4 denom = vclampden(vfma(d, dot, vneg(Vl0)));
        t = vfma(vneg(F), vrcp(denom), t);
    }
    v4 q0 = vfma(t, Vl0, Pl0);
    v4 q1 = vfma(t, Vl1, Pl1);
    v4 q2 = vfma(t, Vl2, Pl2);
    v4 r2 = vfma(q1, q1, vmul(q2, q2));
    v4 wp = vfmas(r2, -cc, one);
    v4 w  = vmaxs(wp, 1e-12f);
    v4 rs = vrsq(w);
    v4 sq = vmul(w, rs);
    v4 d  = vmuls(rs, Cv);
    v4 sv = vfmas(sq, -invC, {invC, invC, invC, invC});
    v4 F  = vsub(sv, q0);

    v4 g1 = vmul(d, q1), g2 = vmul(d, q2);
    v4 nm00 = {-m00,-m00,-m00,-m00}, nm01 = {-m01,-m01,-m01,-m01}, nm02 = {-m02,-m02,-m02,-m02};
    v4 n0 = vfmas(g1, m10, vfmas(g2, m20, nm00));
    v4 n1 = vfmas(g1, m11, vfmas(g2, m21, nm01));
    v4 n2 = vfmas(g1, m12, vfmas(g2, m22, nm02));
    v4 ninv = vrsq(vfma(n0, n0, vfma(n1, n1, vmul(n2, n2))));
    n0 = vmul(n0, ninv); n1 = vmul(n1, ninv); n2 = vmul(n2, ninv);

    float ta[4]  = {t.a, t.b, t.c, t.d};
    float n0a[4] = {n0.a, n0.b, n0.c, n0.d};
    float n1a[4] = {n1.a, n1.b, n1.c, n1.d};
    float n2a[4] = {n2.a, n2.b, n2.c, n2.d};
    float r2a[4] = {r2.a, r2.b, r2.c, r2.d};
    float Fa[4]  = {F.a, F.b, F.c, F.d};
    float wpa[4] = {wp.a, wp.b, wp.c, wp.d};

    // ---- phase 3: n into LDS (scalar el*3 writes, 2/bank free); t/valid
    // direct scalar nt stores (stride-1, 256B/wave full lines) ----
    const size_t ebase = (size_t)blk * 1024;
    #pragma unroll
    for (int k = 0; k < 4; ++k) {
        const int el = k*256 + tid;
        sB[el*3+0] = n0a[k];
        sB[el*3+1] = n1a[k];
        sB[el*3+2] = n2a[k];
        float vd = (r2a[k] <= rmax2 && fabsf(Fa[k]) < 0.001f && wpa[k] > 0.0f) ? 1.0f : 0.0f;
        __builtin_nontemporal_store(ta[k], &t_out[ebase + el]);
        __builtin_nontemporal_store(vd, &valid_out[ebase + el]);
    }
    __syncthreads();

    // ---- stage-out n: contiguous fx4 reads -> full-line 1KB/wave nt stores ----
    __builtin_nontemporal_store(sB4[0*256 + tid], &n_out4[fbase + 0*256 + tid]);
    __builtin_nontemporal_store(sB4[1*256 + tid], &n_out4[fbase + 1*256 + tid]);
    __builtin_nontemporal_store(sB4[2*256 + tid], &n_out4[fbase + 2*256 + tid]);
}

// Scalar tail for N % 1024 != 0 (not hit at N=2^23, but safe).
__global__ void trace_tail_k(const float* __restrict__ P, const float* __restrict__ V,
                             const float* __restrict__ ws,
                             float* __restrict__ t_out, float* __restrict__ n_out,
                             float* __restrict__ valid_out, int start, int N) {
    int i = start + blockIdx.x * blockDim.x + threadIdx.x;
    if (i >= N) return;
    const float m00 = ws[0], m01 = ws[1], m02 = ws[2];
    const float m10 = ws[3], m11 = ws[4], m12 = ws[5];
    const float m20 = ws[6], m21 = ws[7], m22 = ws[8];
    const float b0 = ws[9], b1 = ws[10], b2 = ws[11];
    const float Cv = ws[12], rmax2 = ws[13], cc = ws[14], invC = ws[15];
    float dpx = P[i*3+0] - b0, dpy = P[i*3+1] - b1, dpz = P[i*3+2] - b2;
    float Pl0 = m00*dpx + m01*dpy + m02*dpz;
    float Pl1 = m10*dpx + m11*dpy + m12*dpz;
    float Pl2 = m20*dpx + m21*dpy + m22*dpz;
    float Vl0 = m00*V[i*3+0] + m01*V[i*3+1] + m02*V[i*3+2];
    float Vl1 = m10*V[i*3+0] + m11*V[i*3+1] + m12*V[i*3+2];
    float Vl2 = m20*V[i*3+0] + m21*V[i*3+1] + m22*V[i*3+2];
    float t = 0.0f;
    for (int it = 0; it < 6; ++it) {
        float q1 = Pl1 + t*Vl1, q2 = Pl2 + t*Vl2;
        float r2 = q1*q1 + q2*q2;
        float w  = fmaxf(1.0f - cc*r2, 1e-12f);
        float rs = frsq(w);
        float sq = w * rs;
        float d  = Cv * rs;
        float sv = fmaf(sq, -invC, invC);
        float F  = sv - (Pl0 + t*Vl0);
        float denom = d*(q1*Vl1 + q2*Vl2) - Vl0;
        denom = (fabsf(denom) > 1e-12f) ? denom : 1e-12f;
        t = t - F * frcp(denom);
    }
    float q0 = Pl0 + t*Vl0, q1 = Pl1 + t*Vl1, q2 = Pl2 + t*Vl2;
    float r2 = q1*q1 + q2*q2;
    float wp = 1.0f - cc*r2;
    float w  = fmaxf(wp, 1e-12f);
    float rs = frsq(w);
    float sq = w * rs;
    float d  = Cv * rs;
    float sv = fmaf(sq, -invC, invC);
    float F  = sv - q0;
    bool valid = (r2 <= rmax2) && (fabsf(F) < 0.001f) && (wp > 0.0f);
    float g1 = d*q1, g2 = d*q2;
    float n0 = -m00 + g1*m10 + g2*m20;
    float n1 = -m01 + g1*m11 + g2*m21;
    float n2 = -m02 + g1*m12 + g2*m22;
    float ninv = frsq(n0*n0 + n1*n1 + n2*n2);
    t_out[i] = t;
    n_out[i*3+0] = n0*ninv; n_out[i*3+1] = n1*ninv; n_out[i*3+2] = n2*ninv;
    valid_out[i] = valid ? 1.0f : 0.0f;
}

extern "C" void kernel_launch(void* const* d_in, const int* in_sizes, int n_in,
                              void* d_out, int out_size, void* d_ws, size_t ws_size,
                              hipStream_t stream) {
    const float* P       = (const float*)d_in[0];
    const float* V       = (const float*)d_in[1];
    const float* tf_in   = (const float*)d_in[2];
    const float* dia     = (const float*)d_in[3];
    const float* C       = (const float*)d_in[4];
    const float* anchors = (const float*)d_in[5];
    const float* scale   = (const float*)d_in[6];
    const int N = in_sizes[0] / 3;

    float* out = (float*)d_out;
    float* ws  = (float*)d_ws;

    // Output layout: t[N] | n[3N] | valid[N] | tf_surface[16] | tf_next[16]
    float* t_out     = out;
    float* n_out     = out + (size_t)N;
    float* valid_out = out + (size_t)4*N;
    float* tf_out    = out + (size_t)5*N;

    setup_k<<<1, 1, 0, stream>>>(tf_in, dia, C, anchors, scale, tf_out, ws);

    const int ntiles = N / 1024;
    if (ntiles > 0) {
        trace_k<<<ntiles, 256, 0, stream>>>((const float4*)P, (const float4*)V, ws,
                                            t_out, (fx4*)n_out, valid_out, ntiles);
    }
    const int start = ntiles * 1024;
    const int rem = N - start;
    if (rem > 0) {
        trace_tail_k<<<(rem + 255) / 256, 256, 0, stream>>>(P, V, ws, t_out, n_out,
                                                            valid_out, start, N);
    }
}